// Round 5
// baseline (101.410 us; speedup 1.0000x reference)
//
#include <hip/hip_runtime.h>

typedef __attribute__((ext_vector_type(8))) _Float16 half8;   // MFMA A/B frag (4 VGPR)
typedef __attribute__((ext_vector_type(16))) float f32x16;    // 32x32 MFMA C/D frag
typedef __attribute__((ext_vector_type(4))) float f32x4;
typedef __attribute__((ext_vector_type(4))) unsigned int uint4v;

#define LOG2E 1.44269504088896340736f

__device__ __forceinline__ unsigned short f2h(float x) {
  _Float16 h = (_Float16)x;
  union { _Float16 h; unsigned short u; } v; v.h = h;
  return v.u;
}
__device__ __forceinline__ float h2f(unsigned short u) {
  union { unsigned short u; _Float16 h; } v; v.u = u;
  return (float)v.h;
}
__device__ __forceinline__ unsigned pk2(float a, float b) {  // 2xf32 -> 2xf16
  auto h = __builtin_amdgcn_cvt_pkrtz(a, b);
  return __builtin_bit_cast(unsigned, h);
}

// K image offset within a 64-kv tile (halfs): row r6 (0..63), col (0..127)
__device__ __forceinline__ int kimg(int r6, int col) {
  return r6 * 128 + (((col >> 3) ^ (r6 & 15)) << 3) + (col & 7);
}
// V image offset within tile (halfs, +8192 base): e (0..127), kv-local (0..63)
__device__ __forceinline__ int vimg(int e, int kvl) {
  return 8192 + (e >> 1) * 128 +
         ((((e & 1) << 3) | (kvl >> 3)) ^ ((e >> 1) & 15)) * 8 + (kvl & 7);
}

// ---------------------------------------------------------------------------
// Kernel 0: pack weights: WT[w][n][k] = fp16(W_w[k][n])
// ---------------------------------------------------------------------------
__global__ __launch_bounds__(256) void pack_w(
    const float* __restrict__ Wq, const float* __restrict__ Wk,
    const float* __restrict__ Wv, unsigned short* __restrict__ WT) {
  int idx = blockIdx.x * 256 + threadIdx.x;
  int w = idx >> 15;
  int r = idx & 32767;
  int n = r >> 8;
  int k = r & 255;
  const float* W = (w == 0) ? Wq : ((w == 1) ? Wk : Wv);
  WT[idx] = f2h(W[k * 128 + n]);
}

// ---------------------------------------------------------------------------
// Kernel 1: projections, 1-wave blocks, barrier-free, weights from L2.
// N-split 2: block = (mtile, nh). Writes Qb linear; K/V into pre-swizzled
// KV2 tile images (32KB per 64-token tile: [0,16K)=K img, [16K,32K)=V img).
// grid = 1024 mtiles x 2 = 2048 blocks x 64 thr.
// ---------------------------------------------------------------------------
__global__ __launch_bounds__(64) void proj1(
    const float* __restrict__ seq, const unsigned short* __restrict__ WT,
    unsigned short* __restrict__ Qb, unsigned short* __restrict__ KV2) {
  const int lane = threadIdx.x & 63, lo = lane & 15, hi = lane >> 4;
  const int nh = blockIdx.x & 1;
  const int qb = (blockIdx.x >> 1) * 16;

  half8 a[8];
#pragma unroll
  for (int kb = 0; kb < 8; ++kb) {
    const float* p = &seq[(qb + lo) * 256 + kb * 32 + hi * 8];
    f32x4 x0 = *reinterpret_cast<const f32x4*>(p);
    f32x4 x1 = *reinterpret_cast<const f32x4*>(p + 4);
    half8 v;
    v[0] = (_Float16)x0[0]; v[1] = (_Float16)x0[1];
    v[2] = (_Float16)x0[2]; v[3] = (_Float16)x0[3];
    v[4] = (_Float16)x1[0]; v[5] = (_Float16)x1[1];
    v[6] = (_Float16)x1[2]; v[7] = (_Float16)x1[3];
    a[kb] = v;
  }

  f32x4 aq[4], ak[4], av[4];
  const f32x4 z = {0.f, 0.f, 0.f, 0.f};
#pragma unroll
  for (int e = 0; e < 4; ++e) { aq[e] = z; ak[e] = z; av[e] = z; }

#pragma unroll
  for (int kb = 0; kb < 8; ++kb) {
#pragma unroll
    for (int e4 = 0; e4 < 4; ++e4) {
      const int e8 = nh * 4 + e4;
      const int wrow = (e8 * 16 + lo) * 256 + kb * 32 + hi * 8;
      half8 bq = *reinterpret_cast<const half8*>(&WT[wrow]);
      half8 bk = *reinterpret_cast<const half8*>(&WT[32768 + wrow]);
      half8 bv = *reinterpret_cast<const half8*>(&WT[65536 + wrow]);
      aq[e4] = __builtin_amdgcn_mfma_f32_16x16x32_f16(a[kb], bq, aq[e4], 0, 0, 0);
      ak[e4] = __builtin_amdgcn_mfma_f32_16x16x32_f16(a[kb], bk, ak[e4], 0, 0, 0);
      av[e4] = __builtin_amdgcn_mfma_f32_16x16x32_f16(bv, a[kb], av[e4], 0, 0, 0);
    }
  }
  // C/D layout: col = lane&15, row = (lane>>4)*4 + i
#pragma unroll
  for (int e4 = 0; e4 < 4; ++e4) {
#pragma unroll
    for (int i = 0; i < 4; ++i) {
      const int e8 = nh * 4 + e4;
      const int row = qb + hi * 4 + i;       // token (Q/K)
      const int col = e8 * 16 + lo;          // out-feature (Q/K)
      Qb[row * 128 + col] = f2h(aq[e4][i]);
      // K image
      KV2[(size_t)(row >> 6) * 16384 + kimg(row & 63, col)] = f2h(ak[e4][i]);
      // V^T: e = out-feature, token = qb + lo
      const int e = e8 * 16 + hi * 4 + i;
      const int tok = qb + lo;
      KV2[(size_t)(tok >> 6) * 16384 + vimg(e, tok & 63)] = f2h(av[e4][i]);
    }
  }
}

// ---------------------------------------------------------------------------
// Kernel 2: flash attention, 32x32 swapped-QK^T, KV-split<NS>.
// Block: 256 thr = 4 waves x 32 q-rows (128 q/block); KVBLK=64.
// Staging: global_load_lds from pre-swizzled KV2 images (no reg staging).
// In-register softmax with defer-max; normalized partials to Opart + M to ml.
// grid = 32 qtiles * 4*NS combos.
// ---------------------------------------------------------------------------
template <int NS>
__global__ __launch_bounds__(256, 3) void attn_fa(
    const unsigned short* __restrict__ Qb, const unsigned short* __restrict__ KV2,
    unsigned short* __restrict__ Opart, float* __restrict__ ml) {
  __shared__ __align__(16) unsigned short SM[16384];  // 32KB: K img + V img
  constexpr int NKT = 64 / NS;  // 64-kv tiles per split

  const int tid = threadIdx.x;
  const int wv = tid >> 6, lane = tid & 63, l31 = lane & 31, hi = lane >> 5;
  const int c = blockIdx.x & (4 * NS - 1), t = blockIdx.x / (4 * NS);
  const int b = c / NS, s = c & (NS - 1);
  const int qbw = b * 4096 + t * 128 + wv * 32;
  const int g0 = b * 64 + s * NKT;  // first 64-kv tile index

  // stage tile g: 32KB image -> SM, 8 x 1KB per wave
#define STAGE(G_) do {                                                          \
    const char* src_ = (const char*)KV2 + (size_t)(G_) * 32768;                 \
    _Pragma("unroll")                                                           \
    for (int j = 0; j < 8; ++j) {                                               \
      const int off_ = (wv * 8 + j) * 1024;                                     \
      __builtin_amdgcn_global_load_lds(                                         \
          (const __attribute__((address_space(1))) unsigned int*)(src_ + off_ + lane * 16), \
          (__attribute__((address_space(3))) unsigned int*)((char*)SM + off_),  \
          16, 0, 0);                                                            \
    }                                                                           \
  } while (0)

  half8 qf[8];
#pragma unroll
  for (int kc = 0; kc < 8; ++kc)
    qf[kc] = *reinterpret_cast<const half8*>(&Qb[(qbw + l31) * 128 + kc * 16 + hi * 8]);

  f32x16 acc[4];
#pragma unroll
  for (int et = 0; et < 4; ++et)
#pragma unroll
    for (int r = 0; r < 16; ++r) acc[et][r] = 0.f;

  float mraw = -INFINITY, mL = -INFINITY, lsum = 0.f;

  STAGE(g0);
  asm volatile("s_waitcnt vmcnt(0)" ::: "memory");
  __syncthreads();

  for (int kt = 0; kt < NKT; ++kt) {
    // ---- QK^T: S^T[kv][q], f=0,1 -> kv 0-31 / 32-63 ----
    f32x16 sf[2];
#pragma unroll
    for (int f = 0; f < 2; ++f)
#pragma unroll
      for (int r = 0; r < 16; ++r) sf[f][r] = 0.f;
    __builtin_amdgcn_s_setprio(1);
#pragma unroll
    for (int kc = 0; kc < 8; ++kc) {
#pragma unroll
      for (int f = 0; f < 2; ++f) {
        const int rk = f * 32 + l31;
        half8 kf = *reinterpret_cast<const half8*>(
            &SM[rk * 128 + ((((kc << 1) | hi) ^ (rk & 15)) << 3)]);
        sf[f] = __builtin_amdgcn_mfma_f32_32x32x16_f16(kf, qf[kc], sf[f], 0, 0, 0);
      }
    }
    __builtin_amdgcn_s_setprio(0);

    // ---- in-lane online softmax (q = l31) with defer-max ----
    float tp[16];
#pragma unroll
    for (int r = 0; r < 16; ++r) tp[r] = fmaxf(sf[0][r], sf[1][r]);
#pragma unroll
    for (int r = 0; r < 8; ++r) tp[r] = fmaxf(tp[r], tp[r + 8]);
#pragma unroll
    for (int r = 0; r < 4; ++r) tp[r] = fmaxf(tp[r], tp[r + 4]);
    float smax = fmaxf(fmaxf(tp[0], tp[1]), fmaxf(tp[2], tp[3]));
    smax = fmaxf(smax, __shfl_xor(smax, 32, 64));
    const bool need = (smax * LOG2E) > (mL + 8.0f);  // P bounded by 2^8
    if (__any(need)) {
      const float mnew = fmaxf(mraw, smax);
      const float mLn = mnew * LOG2E;
      const float alpha = exp2f(mL - mLn);
      lsum *= alpha;
#pragma unroll
      for (int et = 0; et < 4; ++et)
#pragma unroll
        for (int r = 0; r < 16; ++r) acc[et][r] *= alpha;
      mraw = mnew; mL = mLn;
    }
#pragma unroll
    for (int f = 0; f < 2; ++f)
#pragma unroll
      for (int r = 0; r < 16; ++r)
        sf[f][r] = exp2f(__builtin_fmaf(sf[f][r], LOG2E, -mL));
    float sp[16];
#pragma unroll
    for (int r = 0; r < 16; ++r) sp[r] = sf[0][r] + sf[1][r];
#pragma unroll
    for (int r = 0; r < 8; ++r) sp[r] = sp[r] + sp[r + 8];
#pragma unroll
    for (int r = 0; r < 4; ++r) sp[r] = sp[r] + sp[r + 4];
    float ssum = (sp[0] + sp[1]) + (sp[2] + sp[3]);
    ssum += __shfl_xor(ssum, 32, 64);
    lsum += ssum;

    // ---- PV: O^T[e][q] += V^T x P (P B-frag assembled in-register) ----
    __builtin_amdgcn_s_setprio(1);
#pragma unroll
    for (int f = 0; f < 2; ++f) {
#pragma unroll
      for (int hf = 0; hf < 2; ++hf) {
        const int rb = hf * 8;
        unsigned w0 = pk2(sf[f][rb + 0], sf[f][rb + 1]);
        unsigned w1 = pk2(sf[f][rb + 2], sf[f][rb + 3]);
        unsigned w2 = pk2(sf[f][rb + 4], sf[f][rb + 5]);
        unsigned w3 = pk2(sf[f][rb + 6], sf[f][rb + 7]);
        unsigned cA = (unsigned)__shfl_xor((int)(hi ? w0 : w2), 32, 64);
        unsigned cB = (unsigned)__shfl_xor((int)(hi ? w1 : w3), 32, 64);
        uint4v pw;
        pw[0] = hi ? cA : w0;
        pw[1] = hi ? cB : w1;
        pw[2] = hi ? w2 : cA;
        pw[3] = hi ? w3 : cB;
        const half8 pa = __builtin_bit_cast(half8, pw);
        const int ks2 = ((f * 2 + hf) << 1) | hi;  // kv chunk 0..7
#pragma unroll
        for (int et = 0; et < 4; ++et) {
          const int e = et * 32 + l31;
          half8 vf = *reinterpret_cast<const half8*>(
              &SM[(64 + (e >> 1)) * 128 +
                  (((((e & 1) << 3) | ks2) ^ ((e >> 1) & 15)) << 3)]);
          acc[et] = __builtin_amdgcn_mfma_f32_32x32x16_f16(vf, pa, acc[et], 0, 0, 0);
        }
      }
    }
    __builtin_amdgcn_s_setprio(0);

    __syncthreads();                       // all waves done reading SM
    if (kt + 1 < NKT) STAGE(g0 + kt + 1);  // DMA next tile
    asm volatile("s_waitcnt vmcnt(0)" ::: "memory");
    __syncthreads();                       // next tile visible
  }

  // ---- epilogue: normalized partial + single M; transpose via SM scratch ----
  unsigned short* T = &SM[wv * 4096];  // 32 q x 128 e, chunk ^= q&15
  const float rinv = 1.0f / lsum;
#pragma unroll
  for (int et = 0; et < 4; ++et)
#pragma unroll
    for (int r = 0; r < 16; r += 2) {
      const int e = et * 32 + (r & 3) + ((r >> 2) << 3) + (hi << 2);
      *reinterpret_cast<unsigned*>(
          &T[l31 * 128 + ((e & 7) | ((((e >> 3) ^ (l31 & 15)) << 3)))]) =
          pk2(acc[et][r] * rinv, acc[et][r + 1] * rinv);
    }
  __syncthreads();
#pragma unroll
  for (int j = 0; j < 8; ++j) {
    const int idx = lane + j * 64;
    const int q = idx >> 4, cc = idx & 15;
    const int grow = qbw + q;
    const int prow = ((grow >> 6) * NS + s) * 64 + (grow & 63);
    *reinterpret_cast<uint4v*>(&Opart[(size_t)prow * 128 + cc * 8]) =
        *reinterpret_cast<const uint4v*>(&T[q * 128 + ((cc ^ (q & 15)) << 3)]);
  }
  if (hi == 0) {
    const int grow = qbw + l31;
    const int prow = ((grow >> 6) * NS + s) * 64 + (grow & 63);
    ml[prow] = mL + __log2f(lsum);
  }
#undef STAGE
}

// ---------------------------------------------------------------------------
// Kernel 3: merge NS normalized partials: O = sum(w_s*Ohat_s)/sum(w_s),
// w_s = 2^(M_s - Mmax).
// ---------------------------------------------------------------------------
template <int NS>
__global__ __launch_bounds__(256) void merge_kernel(
    const unsigned short* __restrict__ Opart, const float* __restrict__ ml,
    float* __restrict__ out) {
  const int idx = blockIdx.x * 256 + threadIdx.x;  // 2097152
  const int r = idx >> 7, col = idx & 127;
  const int qt = r >> 6, rl = r & 63;
  float M[NS];
  float Mmax = -INFINITY;
#pragma unroll
  for (int s = 0; s < NS; ++s) {
    M[s] = ml[(qt * NS + s) * 64 + rl];
    Mmax = fmaxf(Mmax, M[s]);
  }
  float den = 0.f, num = 0.f;
#pragma unroll
  for (int s = 0; s < NS; ++s) {
    const float w = exp2f(M[s] - Mmax);
    den += w;
    num += w * h2f(Opart[(size_t)((qt * NS + s) * 64 + rl) * 128 + col]);
  }
  out[(size_t)r * 128 + col] = num / den;
}

// ---------------------------------------------------------------------------
extern "C" void kernel_launch(void* const* d_in, const int* in_sizes, int n_in,
                              void* d_out, int out_size, void* d_ws, size_t ws_size,
                              hipStream_t stream) {
  const float* seq = (const float*)d_in[0];
  // d_in[1] = lengths: UNUSED by the reference (no masking).
  const float* Wq = (const float*)d_in[2];
  const float* Wk = (const float*)d_in[3];
  const float* Wv = (const float*)d_in[4];
  float* out = (float*)d_out;

  unsigned short* WT  = (unsigned short*)d_ws;       // 98304 halfs
  unsigned short* Qb  = WT + 3 * 128 * 256;          // 16384*128 halfs
  unsigned short* KV2 = Qb + 16384 * 128;            // 256 tiles * 16384 halfs = 8.4MB
  unsigned short* Opart = KV2 + 256 * 16384;         // 16384*NS*128 halfs

  const size_t base_halfs = 98304 + 16384 * 128 + 256 * 16384;
  const size_t need8 = (base_halfs + (size_t)16384 * 8 * 128) * 2 + 16384 * 8 * 4;

  pack_w<<<384, 256, 0, stream>>>(Wq, Wk, Wv, WT);
  proj1<<<2048, 64, 0, stream>>>(seq, WT, Qb, KV2);

  if (ws_size >= need8) {
    float* ml = (float*)(Opart + (size_t)16384 * 8 * 128);
    attn_fa<8><<<32 * 4 * 8, 256, 0, stream>>>(Qb, KV2, Opart, ml);
    merge_kernel<8><<<8192, 256, 0, stream>>>(Opart, ml, out);
  } else {
    float* ml = (float*)(Opart + (size_t)16384 * 4 * 128);
    attn_fa<4><<<32 * 4 * 4, 256, 0, stream>>>(Qb, KV2, Opart, ml);
    merge_kernel<4><<<8192, 256, 0, stream>>>(Opart, ml, out);
  }
}

// Round 6
// 92.184 us; speedup vs baseline: 1.1001x; 1.1001x over previous
//
#include <hip/hip_runtime.h>

typedef __attribute__((ext_vector_type(8))) _Float16 half8;   // MFMA A/B frag (4 VGPR)
typedef __attribute__((ext_vector_type(16))) float f32x16;    // 32x32 MFMA C/D frag
typedef __attribute__((ext_vector_type(8))) float f32x8;
typedef __attribute__((ext_vector_type(4))) float f32x4;
typedef __attribute__((ext_vector_type(4))) unsigned int uint4v;

#define LOG2E 1.44269504088896340736f
#define NS 4          // KV splits
#define NKT (64 / NS) // 64-kv tiles per split

__device__ __forceinline__ unsigned short f2h(float x) {
  _Float16 h = (_Float16)x;
  union { _Float16 h; unsigned short u; } v; v.h = h;
  return v.u;
}
__device__ __forceinline__ float h2f(unsigned short u) {
  union { unsigned short u; _Float16 h; } v; v.u = u;
  return (float)v.h;
}
__device__ __forceinline__ unsigned pk2(float a, float b) {  // 2xf32 -> 2xf16
  auto h = __builtin_amdgcn_cvt_pkrtz(a, b);
  return __builtin_bit_cast(unsigned, h);
}

// K image offset within a 64-kv tile (halfs): row r6 (0..63), col (0..127)
__device__ __forceinline__ int kimg(int r6, int col) {
  return r6 * 128 + (((col >> 3) ^ (r6 & 15)) << 3) + (col & 7);
}
// V image offset within tile (halfs, +8192 base): e (0..127), kv-local (0..63)
__device__ __forceinline__ int vimg(int e, int kvl) {
  return 8192 + (e >> 1) * 128 +
         ((((e & 1) << 3) | (kvl >> 3)) ^ ((e >> 1) & 15)) * 8 + (kvl & 7);
}

// ---------------------------------------------------------------------------
// Kernel 0: pack weights: WT[w][n][k] = fp16(W_w[k][n])
// ---------------------------------------------------------------------------
__global__ __launch_bounds__(256) void pack_w(
    const float* __restrict__ Wq, const float* __restrict__ Wk,
    const float* __restrict__ Wv, unsigned short* __restrict__ WT) {
  int idx = blockIdx.x * 256 + threadIdx.x;
  int w = idx >> 15;
  int r = idx & 32767;
  int n = r >> 8;
  int k = r & 255;
  const float* W = (w == 0) ? Wq : ((w == 1) ? Wk : Wv);
  WT[idx] = f2h(W[k * 128 + n]);
}

// ---------------------------------------------------------------------------
// Kernel 1: projections, 1-wave blocks, barrier-free, weights from L2.
// Q is pre-scaled by LOG2E (softmax runs in log2 domain downstream).
// K/V go to pre-swizzled KV2 tile images (32KB per 64-token tile).
// ---------------------------------------------------------------------------
__global__ __launch_bounds__(64) void proj1(
    const float* __restrict__ seq, const unsigned short* __restrict__ WT,
    unsigned short* __restrict__ Qb, unsigned short* __restrict__ KV2) {
  const int lane = threadIdx.x & 63, lo = lane & 15, hi = lane >> 4;
  const int nh = blockIdx.x & 1;
  const int qb = (blockIdx.x >> 1) * 16;

  half8 a[8];
#pragma unroll
  for (int kb = 0; kb < 8; ++kb) {
    const float* p = &seq[(qb + lo) * 256 + kb * 32 + hi * 8];
    f32x4 x0 = *reinterpret_cast<const f32x4*>(p);
    f32x4 x1 = *reinterpret_cast<const f32x4*>(p + 4);
    half8 v;
    v[0] = (_Float16)x0[0]; v[1] = (_Float16)x0[1];
    v[2] = (_Float16)x0[2]; v[3] = (_Float16)x0[3];
    v[4] = (_Float16)x1[0]; v[5] = (_Float16)x1[1];
    v[6] = (_Float16)x1[2]; v[7] = (_Float16)x1[3];
    a[kb] = v;
  }

  f32x4 aq[4], ak[4], av[4];
  const f32x4 z = {0.f, 0.f, 0.f, 0.f};
#pragma unroll
  for (int e = 0; e < 4; ++e) { aq[e] = z; ak[e] = z; av[e] = z; }

#pragma unroll
  for (int kb = 0; kb < 8; ++kb) {
#pragma unroll
    for (int e4 = 0; e4 < 4; ++e4) {
      const int e8 = nh * 4 + e4;
      const int wrow = (e8 * 16 + lo) * 256 + kb * 32 + hi * 8;
      half8 bq = *reinterpret_cast<const half8*>(&WT[wrow]);
      half8 bk = *reinterpret_cast<const half8*>(&WT[32768 + wrow]);
      half8 bv = *reinterpret_cast<const half8*>(&WT[65536 + wrow]);
      aq[e4] = __builtin_amdgcn_mfma_f32_16x16x32_f16(a[kb], bq, aq[e4], 0, 0, 0);
      ak[e4] = __builtin_amdgcn_mfma_f32_16x16x32_f16(a[kb], bk, ak[e4], 0, 0, 0);
      av[e4] = __builtin_amdgcn_mfma_f32_16x16x32_f16(bv, a[kb], av[e4], 0, 0, 0);
    }
  }
  // C/D layout: col = lane&15, row = (lane>>4)*4 + i
#pragma unroll
  for (int e4 = 0; e4 < 4; ++e4) {
#pragma unroll
    for (int i = 0; i < 4; ++i) {
      const int e8 = nh * 4 + e4;
      const int row = qb + hi * 4 + i;       // token (Q/K)
      const int col = e8 * 16 + lo;          // out-feature (Q/K)
      Qb[row * 128 + col] = f2h(aq[e4][i] * LOG2E);  // log2-domain Q
      KV2[(size_t)(row >> 6) * 16384 + kimg(row & 63, col)] = f2h(ak[e4][i]);
      const int e = e8 * 16 + hi * 4 + i;    // out-feature (V)
      const int tok = qb + lo;
      KV2[(size_t)(tok >> 6) * 16384 + vimg(e, tok & 63)] = f2h(av[e4][i]);
    }
  }
}

// ---------------------------------------------------------------------------
// Kernel 2: flash attention, 32x32 swapped-QK^T, double-buffered stage-early.
// Block: 256 thr = 4 waves x 32 q-rows; KVBLK=64; NS splits of 1024 kv.
// grid = 32 qtiles * 16 (b,s) = 512 blocks (2/CU). One barrier per kt.
// ---------------------------------------------------------------------------
__global__ __launch_bounds__(256, 2) void attn_fa(
    const unsigned short* __restrict__ Qb, const unsigned short* __restrict__ KV2,
    unsigned short* __restrict__ Opart, float* __restrict__ ml) {
  __shared__ __align__(16) unsigned short SM[2][16384];  // 2 x 32KB (K img + V img)
  static_assert(NKT % 2 == 0, "epilogue scratch assumes even NKT");

  const int tid = threadIdx.x;
  const int wv = tid >> 6, lane = tid & 63, l31 = lane & 31, hi = lane >> 5;
  const int c = blockIdx.x & 15, t = blockIdx.x >> 4;
  const int b = c & 3, s = c >> 2;  // XCD = blk&7 -> b = (blk&7)&3: one batch per XCD
  const int qbw = b * 4096 + t * 128 + wv * 32;
  const int g0 = b * 64 + s * NKT;  // first 64-kv tile index
  unsigned short* SMb = &SM[0][0];

#define STAGE(G_, P_) do {                                                      \
    const char* src_ = (const char*)KV2 + (size_t)(G_) * 32768;                 \
    char* dst_ = (char*)SMb + (P_) * 32768;                                     \
    _Pragma("unroll")                                                           \
    for (int j = 0; j < 8; ++j) {                                               \
      const int off_ = (wv * 8 + j) * 1024;                                     \
      __builtin_amdgcn_global_load_lds(                                         \
          (const __attribute__((address_space(1))) unsigned int*)(src_ + off_ + lane * 16), \
          (__attribute__((address_space(3))) unsigned int*)(dst_ + off_),       \
          16, 0, 0);                                                            \
    }                                                                           \
  } while (0)

  half8 qf[8];
#pragma unroll
  for (int kc = 0; kc < 8; ++kc)
    qf[kc] = *reinterpret_cast<const half8*>(&Qb[(qbw + l31) * 128 + kc * 16 + hi * 8]);

  f32x16 acc[4];
#pragma unroll
  for (int et = 0; et < 4; ++et)
#pragma unroll
    for (int r = 0; r < 16; ++r) acc[et][r] = 0.f;

  float m = -INFINITY, lsum = 0.f;  // m in log2 domain; lsum per-half

  int p = 0;
  STAGE(g0, 0);
  asm volatile("s_waitcnt vmcnt(0)" ::: "memory");
  __syncthreads();

  for (int kt = 0; kt < NKT; ++kt) {
    if (kt + 1 < NKT) STAGE(g0 + kt + 1, p ^ 1);  // issue early; flies under compute
    const int pb = p * 16384;

    // ---- QK^T: S^T[kv][q] (log2 domain, Q pre-scaled) ----
    f32x16 sf[2];
#pragma unroll
    for (int f = 0; f < 2; ++f)
#pragma unroll
      for (int r = 0; r < 16; ++r) sf[f][r] = 0.f;
    __builtin_amdgcn_s_setprio(1);
#pragma unroll
    for (int kc = 0; kc < 8; ++kc) {
#pragma unroll
      for (int f = 0; f < 2; ++f) {
        const int rk = f * 32 + l31;
        half8 kf = *reinterpret_cast<const half8*>(
            &SMb[pb + rk * 128 + ((((kc << 1) | hi) ^ (rk & 15)) << 3)]);
        sf[f] = __builtin_amdgcn_mfma_f32_32x32x16_f16(kf, qf[kc], sf[f], 0, 0, 0);
      }
    }
    __builtin_amdgcn_s_setprio(0);

    // ---- in-lane online softmax (q = l31), defer-max, vector trees ----
    f32x16 vm = __builtin_elementwise_max(sf[0], sf[1]);
    f32x8 m8 = __builtin_elementwise_max(
        __builtin_shufflevector(vm, vm, 0, 1, 2, 3, 4, 5, 6, 7),
        __builtin_shufflevector(vm, vm, 8, 9, 10, 11, 12, 13, 14, 15));
    f32x4 m4 = __builtin_elementwise_max(
        __builtin_shufflevector(m8, m8, 0, 1, 2, 3),
        __builtin_shufflevector(m8, m8, 4, 5, 6, 7));
    float smax = fmaxf(fmaxf(m4[0], m4[1]), fmaxf(m4[2], m4[3]));
    smax = fmaxf(smax, __shfl_xor(smax, 32, 64));
    if (__any(smax > m + 8.0f)) {  // P bounded by 2^8
      const float mn = fmaxf(m, smax);
      const float al = exp2f(m - mn);
      lsum *= al;
#pragma unroll
      for (int et = 0; et < 4; ++et) acc[et] = acc[et] * al;
      m = mn;
    }
#pragma unroll
    for (int f = 0; f < 2; ++f) {
      sf[f] = sf[f] - m;
#pragma unroll
      for (int r = 0; r < 16; ++r) sf[f][r] = exp2f(sf[f][r]);
    }
    f32x16 vs = sf[0] + sf[1];
    f32x8 s8 = __builtin_shufflevector(vs, vs, 0, 1, 2, 3, 4, 5, 6, 7) +
               __builtin_shufflevector(vs, vs, 8, 9, 10, 11, 12, 13, 14, 15);
    f32x4 s4 = __builtin_shufflevector(s8, s8, 0, 1, 2, 3) +
               __builtin_shufflevector(s8, s8, 4, 5, 6, 7);
    lsum += (s4[0] + s4[1]) + (s4[2] + s4[3]);  // per-half; cross-half at end

    // ---- PV: O^T[e][q] += V^T x P (P B-frag via permlane32_swap) ----
    __builtin_amdgcn_s_setprio(1);
#pragma unroll
    for (int f = 0; f < 2; ++f) {
#pragma unroll
      for (int hf = 0; hf < 2; ++hf) {
        const int rb = hf * 8;
        unsigned w0 = pk2(sf[f][rb + 0], sf[f][rb + 1]);
        unsigned w1 = pk2(sf[f][rb + 2], sf[f][rb + 3]);
        unsigned w2 = pk2(sf[f][rb + 4], sf[f][rb + 5]);
        unsigned w3 = pk2(sf[f][rb + 6], sf[f][rb + 7]);
        asm("v_permlane32_swap_b32 %0, %1" : "+v"(w0), "+v"(w2));
        asm("v_permlane32_swap_b32 %0, %1" : "+v"(w1), "+v"(w3));
        uint4v pw;
        pw[0] = w0; pw[1] = w1; pw[2] = w2; pw[3] = w3;
        const half8 pa = __builtin_bit_cast(half8, pw);
        const int ks2 = ((f * 2 + hf) << 1) | hi;  // kv chunk 0..7
#pragma unroll
        for (int et = 0; et < 4; ++et) {
          const int e = et * 32 + l31;
          half8 vf = *reinterpret_cast<const half8*>(
              &SMb[pb + 8192 + (e >> 1) * 128 +
                   (((((e & 1) << 3) | ks2) ^ ((e >> 1) & 15)) << 3)]);
          acc[et] = __builtin_amdgcn_mfma_f32_32x32x16_f16(vf, pa, acc[et], 0, 0, 0);
        }
      }
    }
    __builtin_amdgcn_s_setprio(0);

    if (kt + 1 < NKT) {
      asm volatile("s_waitcnt vmcnt(0)" ::: "memory");  // my next-tile loads done
      __syncthreads();  // all staging visible + all reads of buf p done
      p ^= 1;
    }
  }

  // ---- epilogue: normalized partial + single M; transpose via buf0 scratch ----
  unsigned short* T = &SMb[wv * 4096];  // per-wave 8KB in buf0 (p==1 at exit)
  const float ltot = lsum + __shfl_xor(lsum, 32, 64);
  const float rinv = 1.0f / ltot;
#pragma unroll
  for (int et = 0; et < 4; ++et)
#pragma unroll
    for (int r = 0; r < 16; r += 2) {
      const int e = et * 32 + (r & 3) + ((r >> 2) << 3) + (hi << 2);
      *reinterpret_cast<unsigned*>(
          &T[l31 * 128 + ((e & 7) | ((((e >> 3) ^ (l31 & 15)) << 3)))]) =
          pk2(acc[et][r] * rinv, acc[et][r + 1] * rinv);
    }
  __syncthreads();
#pragma unroll
  for (int j = 0; j < 8; ++j) {
    const int idx = lane + j * 64;
    const int q = idx >> 4, cc = idx & 15;
    const int grow = qbw + q;
    const int prow = ((grow >> 6) * NS + s) * 64 + (grow & 63);
    *reinterpret_cast<uint4v*>(&Opart[(size_t)prow * 128 + cc * 8]) =
        *reinterpret_cast<const uint4v*>(&T[q * 128 + ((cc ^ (q & 15)) << 3)]);
  }
  if (hi == 0) {
    const int grow = qbw + l31;
    const int prow = ((grow >> 6) * NS + s) * 64 + (grow & 63);
    ml[prow] = m + __log2f(ltot);
  }
#undef STAGE
}

// ---------------------------------------------------------------------------
// Kernel 3: merge NS normalized partials: O = sum(w_s*Ohat_s)/sum(w_s),
// w_s = 2^(M_s - Mmax).
// ---------------------------------------------------------------------------
__global__ __launch_bounds__(256) void merge_kernel(
    const unsigned short* __restrict__ Opart, const float* __restrict__ ml,
    float* __restrict__ out) {
  const int idx = blockIdx.x * 256 + threadIdx.x;  // 2097152
  const int r = idx >> 7, col = idx & 127;
  const int qt = r >> 6, rl = r & 63;
  float M[NS];
  float Mmax = -INFINITY;
#pragma unroll
  for (int s = 0; s < NS; ++s) {
    M[s] = ml[(qt * NS + s) * 64 + rl];
    Mmax = fmaxf(Mmax, M[s]);
  }
  float den = 0.f, num = 0.f;
#pragma unroll
  for (int s = 0; s < NS; ++s) {
    const float w = exp2f(M[s] - Mmax);
    den += w;
    num += w * h2f(Opart[(size_t)((qt * NS + s) * 64 + rl) * 128 + col]);
  }
  out[(size_t)r * 128 + col] = num / den;
}

// ---------------------------------------------------------------------------
extern "C" void kernel_launch(void* const* d_in, const int* in_sizes, int n_in,
                              void* d_out, int out_size, void* d_ws, size_t ws_size,
                              hipStream_t stream) {
  const float* seq = (const float*)d_in[0];
  // d_in[1] = lengths: UNUSED by the reference (no masking).
  const float* Wq = (const float*)d_in[2];
  const float* Wk = (const float*)d_in[3];
  const float* Wv = (const float*)d_in[4];
  float* out = (float*)d_out;

  unsigned short* WT  = (unsigned short*)d_ws;       // 98304 halfs
  unsigned short* Qb  = WT + 3 * 128 * 256;          // 16384*128 halfs
  unsigned short* KV2 = Qb + 16384 * 128;            // 256 tiles * 16384 halfs
  unsigned short* Opart = KV2 + 256 * 16384;         // 16384*NS*128 halfs
  float* ml = (float*)(Opart + (size_t)16384 * NS * 128);

  pack_w<<<384, 256, 0, stream>>>(Wq, Wk, Wv, WT);
  proj1<<<2048, 64, 0, stream>>>(seq, WT, Qb, KV2);
  attn_fa<<<32 * 4 * NS, 256, 0, stream>>>(Qb, KV2, Opart, ml);
  merge_kernel<<<8192, 256, 0, stream>>>(Opart, ml, out);
}